// Round 21
// baseline (170.366 us; speedup 1.0000x reference)
//
#include <hip/hip_runtime.h>
#include <math.h>

#define B_ 32
#define T_ 2048
#define C_ 96
#define L_ 256
#define BLANK 95

__device__ __forceinline__ float ex2(float x) {
  float r; asm("v_exp_f32 %0, %1" : "=v"(r) : "v"(x)); return r;
}
__device__ __forceinline__ float lg2(float x) {
  float r; asm("v_log_f32 %0, %1" : "=v"(r) : "v"(x)); return r;
}
__device__ __forceinline__ unsigned short f2bf(float f) {  // RNE f32->bf16
  unsigned u = __float_as_uint(f);
  return (unsigned short)((u + 0x7FFFu + ((u >> 16) & 1u)) >> 16);
}
__device__ __forceinline__ float bfu(unsigned short u) {
  return __uint_as_float((unsigned)u << 16);
}
// Wave shifts via DPP (VALU). 0x138 = WAVE_SHR1, 0x130 = WAVE_SHL1.
__device__ __forceinline__ float dpp_shr1_f(float x) {
  return __int_as_float(__builtin_amdgcn_update_dpp(
      0, __float_as_int(x), 0x138, 0xF, 0xF, false));
}
__device__ __forceinline__ int dpp_shr1_i(int x) {
  return __builtin_amdgcn_update_dpp(0, x, 0x138, 0xF, 0xF, false);
}
__device__ __forceinline__ float dpp_shl1_f(float x) {
  return __int_as_float(__builtin_amdgcn_update_dpp(
      0, __float_as_int(x), 0x130, 0xF, 0xF, false));
}
__device__ __forceinline__ int dpp_shl1_i(int x) {
  return __builtin_amdgcn_update_dpp(0, x, 0x130, 0xF, 0xF, false);
}
#define RL(V, J) __int_as_float(__builtin_amdgcn_readlane(__float_as_int(V), (J)))

// ---- Kernel 1: fused softmax + per-lane label-prob gather/pack ----
__global__ __launch_bounds__(64) void gather_pack(const float* __restrict__ logits,
                                                  const int* __restrict__ labels,
                                                  float* __restrict__ blanks2,
                                                  ushort4* __restrict__ packed) {
  const int tid = threadIdx.x;
  const int bt = blockIdx.x;  // b*T + t
  const int b = bt >> 11;
  const float* xr = logits + (size_t)bt * C_;
  float xa = xr[tid];
  float xb = (tid < 32) ? xr[64 + tid] : -1.0e30f;
  float m = fmaxf(xa, xb);
#pragma unroll
  for (int off = 32; off >= 1; off >>= 1) m = fmaxf(m, __shfl_xor(m, off));
  float ea = __expf(xa - m);
  float eb = (tid < 32) ? __expf(xb - m) : 0.f;
  float z = ea + eb;
#pragma unroll
  for (int off = 32; off >= 1; off >>= 1) z += __shfl_xor(z, off);
  float rz = 1.0f / z;
  __shared__ float sp[C_];
  sp[tid] = fmaf(ea, rz, 1e-7f);
  if (tid < 32) sp[64 + tid] = fmaf(eb, rz, 1e-7f);
  __syncthreads();
  const int4 lb = *reinterpret_cast<const int4*>(labels + (b << 8) + 4 * tid);
  ushort4 o;
  o.x = f2bf(sp[lb.x]); o.y = f2bf(sp[lb.y]);
  o.z = f2bf(sp[lb.z]); o.w = f2bf(sp[lb.w]);
  packed[(size_t)bt * 64 + tid] = o;
  if (tid < 2) blanks2[2 * bt + tid] = sp[BLANK];
}

// ---------------- Kernel 2: fused fwd+bwd CTC DP, one wave per batch ----
// Both chains (alpha forward from t=0, beta backward from t=Tb-1) live in
// ONE wave's registers and interleave in one instruction stream -- each
// chain's dependency/hazard stalls are filled by the other's instructions.
// tm = (Tb+1)>>1 makes the two chains' step counts equal (+-1).
// Numerics = R19 (grouped frames of 16, inflow-aware pin, exact integer-
// ldexp conversions). JOIN FIX vs R20: (1) final pin of both chains after
// the tails (tails run up to 16 unpinned steps -> lane max decays ~100
// bits; R20's raw product a*b underflowed to 0 -> all-dead join);
// (2) join uses lg2(a)+lg2(b) separately (no product formed at all).

#define LEANF(QU, QB, DI) do {                                               \
    const float b1a = ldexpf(b1_raw, (DI));                                  \
    const float na7 = fmaf(m7, a5, a7 + a6) * p7f;                           \
    const float b1n = dpp_shr1_f(na7);                                       \
    at = (at + a7) * pbf;                                                    \
    a6 = (a6 + a5) * pbf;                                                    \
    a5 = fmaf(m5, a3, a5 + a4) * p5f;                                        \
    a4 = (a4 + a3) * pbf;                                                    \
    a3 = fmaf(m3, a1, a3 + a2) * p3f;                                        \
    a2 = (a2 + a1) * pbf;                                                    \
    a1 = fmaf(m1, b1a, a1 + a0) * p1f;                                       \
    a0 = (a0 + b1a) * pbf;                                                   \
    a7 = na7;                                                                \
    b1_raw = b1n;                                                            \
    p1f = bfu((QU).x); p3f = bfu((QU).y);                                    \
    p5f = bfu((QU).z); p7f = bfu((QU).w);                                    \
    pbf = (QB);                                                              \
  } while (0)

#define SYNCF do {                                                           \
    const float mA = fmaxf(fmaxf(a0, a1), a2);                               \
    const float mB = fmaxf(fmaxf(a3, a4), a5);                               \
    const float mC = fmaxf(fmaxf(a6, a7), at);                               \
    const float m8 = fmaxf(fmaxf(mA, mB), mC);                               \
    const int e_res = (int)((__float_as_uint(m8) >> 23) & 255u) - 126;       \
    const int e_in =                                                         \
        (int)((__float_as_uint(b1_raw) >> 23) & 255u) - 126 + di_f;          \
    const int e = (e_res > e_in) ? e_res : e_in;                             \
    F_f += e;                                                                \
    const int Fp1 = dpp_shr1_i(F_f);                                         \
    const int d1 = g0 ? 0 : (Fp1 - F_f);                                     \
    const int s1 = (d1 > 4) ? (d1 - 4) : 0;                                  \
    F_f += s1;                                                               \
    const int Fp2 = dpp_shr1_i(F_f);                                         \
    const int d2 = g0 ? 0 : (Fp2 - F_f);                                     \
    const int s2 = (d2 > 4) ? (d2 - 4) : 0;                                  \
    F_f += s2;                                                               \
    const int sh = e + s1 + s2;                                              \
    a0 = ldexpf(a0, -sh); a1 = ldexpf(a1, -sh); a2 = ldexpf(a2, -sh);        \
    a3 = ldexpf(a3, -sh); a4 = ldexpf(a4, -sh); a5 = ldexpf(a5, -sh);        \
    a6 = ldexpf(a6, -sh); a7 = ldexpf(a7, -sh); at = ldexpf(at, -sh);        \
    b1_raw = ldexpf(b1_raw, di_f - sh);                                      \
    di_f = d2 - s2;                                                          \
  } while (0)

// Bwd lean: u0 = sender's nb0 (beta[8l+8]); v = sender's nb1*p1_next.
#define LEANB(QU, QB, DI) do {                                               \
    const float x0 = ldexpf(u0, (DI));                                       \
    const float yv = ldexpf(v, (DI));                                        \
    const float cp0 = b0 * pbb, cp1 = b1 * p1b, cp2 = b2 * pbb,              \
                cp3 = b3 * p3b, cp4 = b4 * pbb, cp5 = b5 * p5b,              \
                cp6 = b6 * pbb, cp7 = b7 * p7b, cpt = bt * pbb;              \
    const float x0e = g63 ? cpt : (x0 * pbb);                                \
    const float nb0 = cp0 + cp1;                                             \
    const float nb1 = fmaf(m3, cp3, cp1 + cp2);                              \
    b2 = cp2 + cp3;                                                          \
    b3 = fmaf(m5, cp5, cp3 + cp4);                                           \
    b4 = cp4 + cp5;                                                          \
    b5 = fmaf(m7, cp7, cp5 + cp6);                                           \
    b6 = cp6 + cp7;                                                          \
    b7 = fmaf(mn, yv, cp7 + x0e);                                            \
    bt = cpt;                                                                \
    b0 = nb0; b1 = nb1;                                                      \
    p1b = bfu((QU).x); p3b = bfu((QU).y);                                    \
    p5b = bfu((QU).z); p7b = bfu((QU).w);                                    \
    pbb = (QB);                                                              \
    u0 = dpp_shl1_f(nb0);                                                    \
    v = dpp_shl1_f(nb1 * p1b);                                               \
  } while (0)

#define SYNCB do {                                                           \
    const float mA = fmaxf(fmaxf(b0, b1), b2);                               \
    const float mB = fmaxf(fmaxf(b3, b4), b5);                               \
    const float mC = fmaxf(fmaxf(b6, b7), bt);                               \
    const float m8 = fmaxf(fmaxf(mA, mB), mC);                               \
    const float mi = fmaxf(u0, v);                                           \
    const int e_res = (int)((__float_as_uint(m8) >> 23) & 255u) - 126;       \
    const int e_in =                                                         \
        (int)((__float_as_uint(mi) >> 23) & 255u) - 126 + di_b;              \
    const int e = (e_res > e_in) ? e_res : e_in;                             \
    F_b += e;                                                                \
    const int Fp1 = dpp_shl1_i(F_b);                                         \
    const int d1 = g63 ? 0 : (Fp1 - F_b);                                    \
    const int s1 = (d1 > 4) ? (d1 - 4) : 0;                                  \
    F_b += s1;                                                               \
    const int Fp2 = dpp_shl1_i(F_b);                                         \
    const int d2 = g63 ? 0 : (Fp2 - F_b);                                    \
    const int s2 = (d2 > 4) ? (d2 - 4) : 0;                                  \
    F_b += s2;                                                               \
    const int sh = e + s1 + s2;                                              \
    b0 = ldexpf(b0, -sh); b1 = ldexpf(b1, -sh); b2 = ldexpf(b2, -sh);        \
    b3 = ldexpf(b3, -sh); b4 = ldexpf(b4, -sh); b5 = ldexpf(b5, -sh);        \
    b6 = ldexpf(b6, -sh); b7 = ldexpf(b7, -sh); bt = ldexpf(bt, -sh);        \
    u0 = ldexpf(u0, di_b - sh);                                              \
    v = ldexpf(v, di_b - sh);                                                \
    di_b = d2 - s2;                                                          \
  } while (0)

// Joint slot: one fwd step + one bwd step (independent dataflows -> the
// compiler interleaves them, filling each chain's stalls), then reload.
#define JSLOT(U, DIF, DIB, FRB, BRB) do {                                    \
    LEANF(fq##U, RL(FRB, (U) & 7), DIF);                                     \
    LEANB(bq##U, RL(BRB, (U) & 7), DIB);                                     \
    fq##U = gp[(size_t)(ttf + 17 + U) * 64 + lane];                          \
    bq##U = gp[(size_t)(ttb - 17 - U) * 64 + lane];                          \
  } while (0)

__global__ __launch_bounds__(64) void ctc_dp(const ushort4* __restrict__ packed,
                                             const float* __restrict__ blanks2,
                                             const int* __restrict__ labels,
                                             const int* __restrict__ widths,
                                             const int* __restrict__ lengths,
                                             float* __restrict__ out) {
  const int bat = blockIdx.x;
  const int lane = threadIdx.x;
  const int l8 = lane & 7;
  const int lpar = lane & 1;
  const bool g0 = (lane == 0);
  const bool g63 = (lane == 63);
  const int Tb = widths[bat] >> 3;   // in [1536, 2048]
  const int s_end = 2 * lengths[bat];
  const int tm = (Tb + 1) >> 1;      // equal fwd/bwd step counts (+-1)
  const int* lab = labels + (bat << 8);
  const int4 lb = *reinterpret_cast<const int4*>(lab + 4 * lane);
  const int pw = __shfl_up(lb.w, 1);
  const float m1 = (lane > 0 && lb.x != pw) ? 1.f : 0.f;
  const float m3 = (lb.y != lb.x) ? 1.f : 0.f;
  const float m5 = (lb.z != lb.y) ? 1.f : 0.f;
  const float m7 = (lb.w != lb.z) ? 1.f : 0.f;
  const float mdn = __shfl_down(m1, 1);
  const float mn = g63 ? 0.f : mdn;  // skip mask for s+2 = 8l+9

  const ushort4* gp = packed + (size_t)bat * (T_ * 64);
  const float* gb = blanks2 + bat * (2 * T_);

  // ---------------- fwd prologue ----------------
  const ushort4 fr0v = gp[lane];
  const float bl0 = gb[lpar];
  const ushort4 fr1v = gp[64 + lane];
  const float bl1 = gb[2 + lpar];
  ushort4 fq0 = gp[2 * 64 + lane],  fq1 = gp[3 * 64 + lane];
  ushort4 fq2 = gp[4 * 64 + lane],  fq3 = gp[5 * 64 + lane];
  ushort4 fq4 = gp[6 * 64 + lane],  fq5 = gp[7 * 64 + lane];
  ushort4 fq6 = gp[8 * 64 + lane],  fq7 = gp[9 * 64 + lane];
  ushort4 fq8 = gp[10 * 64 + lane], fq9 = gp[11 * 64 + lane];
  ushort4 fq10 = gp[12 * 64 + lane], fq11 = gp[13 * 64 + lane];
  ushort4 fq12 = gp[14 * 64 + lane], fq13 = gp[15 * 64 + lane];
  ushort4 fq14 = gp[16 * 64 + lane], fq15 = gp[17 * 64 + lane];
  float frA0 = gb[2 * (2 + l8)];
  float frA1 = gb[2 * (10 + l8)];

  float a0 = 0.f, a1 = 0.f, a2 = 0.f, a3 = 0.f;
  float a4 = 0.f, a5 = 0.f, a6 = 0.f, a7 = 0.f, at = 0.f;
  int F_f = 0, di_f = 0;
  float b1_raw = 0.f;
  if (g0) { a0 = bl0; a1 = bfu(fr0v.x); }
  float pbf = bl1;
  float p1f = bfu(fr1v.x), p3f = bfu(fr1v.y);
  float p5f = bfu(fr1v.z), p7f = bfu(fr1v.w);

  // ---------------- bwd prologue ----------------
  const ushort4 brv = gp[(size_t)(Tb - 1) * 64 + lane];
  const float bli = gb[2 * (Tb - 1) + lpar];
  ushort4 bq0 = gp[(size_t)(Tb - 2) * 64 + lane],  bq1 = gp[(size_t)(Tb - 3) * 64 + lane];
  ushort4 bq2 = gp[(size_t)(Tb - 4) * 64 + lane],  bq3 = gp[(size_t)(Tb - 5) * 64 + lane];
  ushort4 bq4 = gp[(size_t)(Tb - 6) * 64 + lane],  bq5 = gp[(size_t)(Tb - 7) * 64 + lane];
  ushort4 bq6 = gp[(size_t)(Tb - 8) * 64 + lane],  bq7 = gp[(size_t)(Tb - 9) * 64 + lane];
  ushort4 bq8 = gp[(size_t)(Tb - 10) * 64 + lane], bq9 = gp[(size_t)(Tb - 11) * 64 + lane];
  ushort4 bq10 = gp[(size_t)(Tb - 12) * 64 + lane], bq11 = gp[(size_t)(Tb - 13) * 64 + lane];
  ushort4 bq12 = gp[(size_t)(Tb - 14) * 64 + lane], bq13 = gp[(size_t)(Tb - 15) * 64 + lane];
  ushort4 bq14 = gp[(size_t)(Tb - 16) * 64 + lane], bq15 = gp[(size_t)(Tb - 17) * 64 + lane];
  float brA0 = gb[2 * (Tb - 2 - l8)];
  float brA1 = gb[2 * (Tb - 10 - l8)];

  const int sb = 8 * lane;
  float b0 = (sb + 0 == s_end || sb + 0 == s_end - 1) ? 1.f : 0.f;
  float b1 = (sb + 1 == s_end || sb + 1 == s_end - 1) ? 1.f : 0.f;
  float b2 = (sb + 2 == s_end || sb + 2 == s_end - 1) ? 1.f : 0.f;
  float b3 = (sb + 3 == s_end || sb + 3 == s_end - 1) ? 1.f : 0.f;
  float b4 = (sb + 4 == s_end || sb + 4 == s_end - 1) ? 1.f : 0.f;
  float b5 = (sb + 5 == s_end || sb + 5 == s_end - 1) ? 1.f : 0.f;
  float b6 = (sb + 6 == s_end || sb + 6 == s_end - 1) ? 1.f : 0.f;
  float b7 = (sb + 7 == s_end || sb + 7 == s_end - 1) ? 1.f : 0.f;
  float bt = (g63 && s_end == 512) ? 1.f : 0.f;
  int F_b = 0, di_b = 0;

  float pbb = bli;
  float p1b = bfu(brv.x), p3b = bfu(brv.y);
  float p5b = bfu(brv.z), p7b = bfu(brv.w);
  float u0 = dpp_shl1_f(b0);
  float v = dpp_shl1_f(b1 * p1b);

  // ---------------- joint main loop ----------------
  int ttf = 1, ttb = Tb - 1;
  while (ttf + 16 <= tm && ttb - 15 >= tm) {
    const float frB0 = gb[2 * (ttf + 17 + l8)];
    const float frB1 = gb[2 * (ttf + 25 + l8)];
    const float brB0 = gb[2 * (ttb - 17 - l8)];
    const float brB1 = gb[2 * (ttb - 25 - l8)];
    JSLOT(0, 0, 0, frA0, brA0);
    JSLOT(1, di_f, di_b, frA0, brA0);
    JSLOT(2, di_f, di_b, frA0, brA0);
    JSLOT(3, di_f, di_b, frA0, brA0);
    JSLOT(4, di_f, di_b, frA0, brA0);
    JSLOT(5, di_f, di_b, frA0, brA0);
    JSLOT(6, di_f, di_b, frA0, brA0);
    JSLOT(7, di_f, di_b, frA0, brA0);
    JSLOT(8, di_f, di_b, frA1, brA1);
    JSLOT(9, di_f, di_b, frA1, brA1);
    JSLOT(10, di_f, di_b, frA1, brA1);
    JSLOT(11, di_f, di_b, frA1, brA1);
    JSLOT(12, di_f, di_b, frA1, brA1);
    JSLOT(13, di_f, di_b, frA1, brA1);
    JSLOT(14, di_f, di_b, frA1, brA1);
    JSLOT(15, di_f, di_b, frA1, brA1);
    SYNCF;
    SYNCB;
    frA0 = frB0; frA1 = frB1; brA0 = brB0; brA1 = brB1;
    ttf += 16; ttb -= 16;
  }

  // ---------------- tails (each <= 16 steps, post-SYNC) ----------------
  if (ttf + 0 < tm)  LEANF(fq0,  RL(frA0, 0), 0);
  if (ttf + 1 < tm)  LEANF(fq1,  RL(frA0, 1), di_f);
  if (ttf + 2 < tm)  LEANF(fq2,  RL(frA0, 2), di_f);
  if (ttf + 3 < tm)  LEANF(fq3,  RL(frA0, 3), di_f);
  if (ttf + 4 < tm)  LEANF(fq4,  RL(frA0, 4), di_f);
  if (ttf + 5 < tm)  LEANF(fq5,  RL(frA0, 5), di_f);
  if (ttf + 6 < tm)  LEANF(fq6,  RL(frA0, 6), di_f);
  if (ttf + 7 < tm)  LEANF(fq7,  RL(frA0, 7), di_f);
  if (ttf + 8 < tm)  LEANF(fq8,  RL(frA1, 0), di_f);
  if (ttf + 9 < tm)  LEANF(fq9,  RL(frA1, 1), di_f);
  if (ttf + 10 < tm) LEANF(fq10, RL(frA1, 2), di_f);
  if (ttf + 11 < tm) LEANF(fq11, RL(frA1, 3), di_f);
  if (ttf + 12 < tm) LEANF(fq12, RL(frA1, 4), di_f);
  if (ttf + 13 < tm) LEANF(fq13, RL(frA1, 5), di_f);
  if (ttf + 14 < tm) LEANF(fq14, RL(frA1, 6), di_f);
  if (ttf + 15 < tm) LEANF(fq15, RL(frA1, 7), di_f);

  if (ttb - 0 >= tm)  LEANB(bq0,  RL(brA0, 0), 0);
  if (ttb - 1 >= tm)  LEANB(bq1,  RL(brA0, 1), di_b);
  if (ttb - 2 >= tm)  LEANB(bq2,  RL(brA0, 2), di_b);
  if (ttb - 3 >= tm)  LEANB(bq3,  RL(brA0, 3), di_b);
  if (ttb - 4 >= tm)  LEANB(bq4,  RL(brA0, 4), di_b);
  if (ttb - 5 >= tm)  LEANB(bq5,  RL(brA0, 5), di_b);
  if (ttb - 6 >= tm)  LEANB(bq6,  RL(brA0, 6), di_b);
  if (ttb - 7 >= tm)  LEANB(bq7,  RL(brA0, 7), di_b);
  if (ttb - 8 >= tm)  LEANB(bq8,  RL(brA1, 0), di_b);
  if (ttb - 9 >= tm)  LEANB(bq9,  RL(brA1, 1), di_b);
  if (ttb - 10 >= tm) LEANB(bq10, RL(brA1, 2), di_b);
  if (ttb - 11 >= tm) LEANB(bq11, RL(brA1, 3), di_b);
  if (ttb - 12 >= tm) LEANB(bq12, RL(brA1, 4), di_b);
  if (ttb - 13 >= tm) LEANB(bq13, RL(brA1, 5), di_b);
  if (ttb - 14 >= tm) LEANB(bq14, RL(brA1, 6), di_b);
  if (ttb - 15 >= tm) LEANB(bq15, RL(brA1, 7), di_b);

  // ---------------- final pins (tails ran unpinned up to 16 steps) ------
  {
    const float mA = fmaxf(fmaxf(a0, a1), a2);
    const float mB = fmaxf(fmaxf(a3, a4), a5);
    const float mC = fmaxf(fmaxf(a6, a7), at);
    const float m8 = fmaxf(fmaxf(mA, mB), mC);
    const int e = (int)((__float_as_uint(m8) >> 23) & 255u) - 126;
    F_f += e;
    a0 = ldexpf(a0, -e); a1 = ldexpf(a1, -e); a2 = ldexpf(a2, -e);
    a3 = ldexpf(a3, -e); a4 = ldexpf(a4, -e); a5 = ldexpf(a5, -e);
    a6 = ldexpf(a6, -e); a7 = ldexpf(a7, -e); at = ldexpf(at, -e);
  }
  {
    const float mA = fmaxf(fmaxf(b0, b1), b2);
    const float mB = fmaxf(fmaxf(b3, b4), b5);
    const float mC = fmaxf(fmaxf(b6, b7), bt);
    const float m8 = fmaxf(fmaxf(mA, mB), mC);
    const int e = (int)((__float_as_uint(m8) >> 23) & 255u) - 126;
    F_b += e;
    b0 = ldexpf(b0, -e); b1 = ldexpf(b1, -e); b2 = ldexpf(b2, -e);
    b3 = ldexpf(b3, -e); b4 = ldexpf(b4, -e); b5 = ldexpf(b5, -e);
    b6 = ldexpf(b6, -e); b7 = ldexpf(b7, -e); bt = ldexpf(bt, -e);
  }

  // ---------------- in-register join (separate logs: no underflow) ------
  const float Ff = (float)(F_f + F_b);
  float t0 = (a0 > 0.f && b0 > 0.f) ? lg2(a0) + lg2(b0) + Ff : -1.0e30f;
  float t1 = (a1 > 0.f && b1 > 0.f) ? lg2(a1) + lg2(b1) + Ff : -1.0e30f;
  float t2 = (a2 > 0.f && b2 > 0.f) ? lg2(a2) + lg2(b2) + Ff : -1.0e30f;
  float t3 = (a3 > 0.f && b3 > 0.f) ? lg2(a3) + lg2(b3) + Ff : -1.0e30f;
  float t4 = (a4 > 0.f && b4 > 0.f) ? lg2(a4) + lg2(b4) + Ff : -1.0e30f;
  float t5 = (a5 > 0.f && b5 > 0.f) ? lg2(a5) + lg2(b5) + Ff : -1.0e30f;
  float t6 = (a6 > 0.f && b6 > 0.f) ? lg2(a6) + lg2(b6) + Ff : -1.0e30f;
  float t7 = (a7 > 0.f && b7 > 0.f) ? lg2(a7) + lg2(b7) + Ff : -1.0e30f;
  float t8 = (g63 && at > 0.f && bt > 0.f) ? lg2(at) + lg2(bt) + Ff : -1.0e30f;
  float M = fmaxf(fmaxf(fmaxf(t0, t1), fmaxf(t2, t3)),
                  fmaxf(fmaxf(t4, t5), fmaxf(fmaxf(t6, t7), t8)));
#pragma unroll
  for (int off = 32; off >= 1; off >>= 1) M = fmaxf(M, __shfl_xor(M, off));
  float sm = ex2(t0 - M) + ex2(t1 - M) + ex2(t2 - M) + ex2(t3 - M) +
             ex2(t4 - M) + ex2(t5 - M) + ex2(t6 - M) + ex2(t7 - M) +
             ex2(t8 - M);
#pragma unroll
  for (int off = 32; off >= 1; off >>= 1) sm += __shfl_xor(sm, off);
  if (g0)
    out[bat] = -0.6931471805599453f * (M + lg2(sm));
}

extern "C" void kernel_launch(void* const* d_in, const int* in_sizes, int n_in,
                              void* d_out, int out_size, void* d_ws, size_t ws_size,
                              hipStream_t stream) {
  const int* labels = (const int*)d_in[0];
  const float* logits = (const float*)d_in[1];
  const int* widths = (const int*)d_in[2];
  const int* lengths = (const int*)d_in[3];
  float* out = (float*)d_out;

  // ws layout: [blanks2: B*T*2 fp32 = 512KB][packed: B*T*64 ushort4 = 32MB]
  float* blanks2 = (float*)d_ws;
  ushort4* packed = (ushort4*)((char*)d_ws + (size_t)B_ * T_ * 2 * sizeof(float));

  gather_pack<<<B_ * T_, 64, 0, stream>>>(logits, labels, blanks2, packed);
  ctc_dp<<<B_, 64, 0, stream>>>(packed, blanks2, labels, widths, lengths, out);
}

// Round 22
// 106.190 us; speedup vs baseline: 1.6044x; 1.6044x over previous
//
#include <hip/hip_runtime.h>
#include <math.h>

#define B_ 32
#define T_ 2048
#define C_ 96
#define L_ 256
#define BLANK 95

__device__ __forceinline__ float ex2(float x) {
  float r; asm("v_exp_f32 %0, %1" : "=v"(r) : "v"(x)); return r;
}
__device__ __forceinline__ float lg2(float x) {
  float r; asm("v_log_f32 %0, %1" : "=v"(r) : "v"(x)); return r;
}
// Wave shifts via DPP (VALU). 0x138 = WAVE_SHR1, 0x130 = WAVE_SHL1.
__device__ __forceinline__ float dpp_shr1_f(float x) {
  return __int_as_float(__builtin_amdgcn_update_dpp(
      0, __float_as_int(x), 0x138, 0xF, 0xF, false));
}
__device__ __forceinline__ int dpp_shr1_i(int x) {
  return __builtin_amdgcn_update_dpp(0, x, 0x138, 0xF, 0xF, false);
}
__device__ __forceinline__ float dpp_shl1_f(float x) {
  return __int_as_float(__builtin_amdgcn_update_dpp(
      0, __float_as_int(x), 0x130, 0xF, 0xF, false));
}
__device__ __forceinline__ int dpp_shl1_i(int x) {
  return __builtin_amdgcn_update_dpp(0, x, 0x130, 0xF, 0xF, false);
}
#define RL(V, J) __int_as_float(__builtin_amdgcn_readlane(__float_as_int(V), (J)))

// ---- Kernel 1: fused softmax + per-lane label-prob gather (fp32) ----
__global__ __launch_bounds__(64) void gather_pack(const float* __restrict__ logits,
                                                  const int* __restrict__ labels,
                                                  float* __restrict__ blanks2,
                                                  float4* __restrict__ packed) {
  const int tid = threadIdx.x;
  const int bt = blockIdx.x;  // b*T + t
  const int b = bt >> 11;
  const float* xr = logits + (size_t)bt * C_;
  float xa = xr[tid];
  float xb = (tid < 32) ? xr[64 + tid] : -1.0e30f;
  float m = fmaxf(xa, xb);
#pragma unroll
  for (int off = 32; off >= 1; off >>= 1) m = fmaxf(m, __shfl_xor(m, off));
  float ea = __expf(xa - m);
  float eb = (tid < 32) ? __expf(xb - m) : 0.f;
  float z = ea + eb;
#pragma unroll
  for (int off = 32; off >= 1; off >>= 1) z += __shfl_xor(z, off);
  float rz = 1.0f / z;
  __shared__ float sp[C_];
  sp[tid] = fmaf(ea, rz, 1e-7f);
  if (tid < 32) sp[64 + tid] = fmaf(eb, rz, 1e-7f);
  __syncthreads();
  const int4 lb = *reinterpret_cast<const int4*>(labels + (b << 8) + 4 * tid);
  float4 o;
  o.x = sp[lb.x]; o.y = sp[lb.y]; o.z = sp[lb.z]; o.w = sp[lb.w];
  packed[(size_t)bt * 64 + tid] = o;
  if (tid < 2) blanks2[2 * bt + tid] = sp[BLANK];
}

// ---------------- Kernel 2: meet-in-the-middle CTC DP ----------------
// R19 structure (best measured: two waves per batch, each chain solo on
// its SIMD -- chain wall time = steps x per-step latency; instruction
// count is the lever at ~6.5 cyc/instr). fp32 probs remove the 4 bf16
// unpack instructions per step. Numerics = R19: grouped frames of 16,
// INFLOW-AWARE PIN (e = max(e_residents, e(b1_raw)+di)) -> converted
// inflow <= 2 exactly, no clamp, no overflow; di_g = d2-s2 <= 4.

#define LEANF(QU, QB, DI) do {                                               \
    const float b1a = ldexpf(b1_raw, (DI));                                  \
    const float na7 = fmaf(m7, a5, a7 + a6) * p7;                            \
    const float b1n = dpp_shr1_f(na7);                                       \
    at = (at + a7) * pb;                                                     \
    a6 = (a6 + a5) * pb;                                                     \
    a5 = fmaf(m5, a3, a5 + a4) * p5;                                         \
    a4 = (a4 + a3) * pb;                                                     \
    a3 = fmaf(m3, a1, a3 + a2) * p3;                                         \
    a2 = (a2 + a1) * pb;                                                     \
    a1 = fmaf(m1, b1a, a1 + a0) * p1;                                        \
    a0 = (a0 + b1a) * pb;                                                    \
    a7 = na7;                                                                \
    b1_raw = b1n;                                                            \
    p1 = (QU).x; p3 = (QU).y; p5 = (QU).z; p7 = (QU).w;                      \
    pb = (QB);                                                               \
  } while (0)

#define SYNCF do {                                                           \
    const float mA = fmaxf(fmaxf(a0, a1), a2);                               \
    const float mB = fmaxf(fmaxf(a3, a4), a5);                               \
    const float mC = fmaxf(fmaxf(a6, a7), at);                               \
    const float m8 = fmaxf(fmaxf(mA, mB), mC);                               \
    const int e_res = (int)((__float_as_uint(m8) >> 23) & 255u) - 126;       \
    const int e_in =                                                         \
        (int)((__float_as_uint(b1_raw) >> 23) & 255u) - 126 + di_g;          \
    const int e = (e_res > e_in) ? e_res : e_in;                             \
    F += e;                                                                  \
    const int Fp1 = dpp_shr1_i(F);                                           \
    const int d1 = g0 ? 0 : (Fp1 - F);                                       \
    const int s1 = (d1 > 4) ? (d1 - 4) : 0;                                  \
    F += s1;                                                                 \
    const int Fp2 = dpp_shr1_i(F);                                           \
    const int d2 = g0 ? 0 : (Fp2 - F);                                       \
    const int s2 = (d2 > 4) ? (d2 - 4) : 0;                                  \
    F += s2;                                                                 \
    const int sh = e + s1 + s2;                                              \
    a0 = ldexpf(a0, -sh); a1 = ldexpf(a1, -sh); a2 = ldexpf(a2, -sh);        \
    a3 = ldexpf(a3, -sh); a4 = ldexpf(a4, -sh); a5 = ldexpf(a5, -sh);        \
    a6 = ldexpf(a6, -sh); a7 = ldexpf(a7, -sh); at = ldexpf(at, -sh);        \
    b1_raw = ldexpf(b1_raw, di_g - sh);                                      \
    di_g = d2 - s2;                                                          \
  } while (0)

#define SLOTF(U, DI, RB) do {                                                \
    LEANF(q##U, RL(RB, (U) & 7), DI);                                        \
    q##U = gp[(size_t)(tt + 17 + U) * 64 + lane];                            \
  } while (0)

// Bwd lean: u0 = sender's nb0 (beta[8l+8]); v = sender's nb1*p1_next.
#define LEANB(QU, QB, DI) do {                                               \
    const float x0 = ldexpf(u0, (DI));                                       \
    const float yv = ldexpf(v, (DI));                                        \
    const float cp0 = b0 * pb, cp1 = b1 * p1, cp2 = b2 * pb, cp3 = b3 * p3,  \
                cp4 = b4 * pb, cp5 = b5 * p5, cp6 = b6 * pb, cp7 = b7 * p7,  \
                cpt = bt * pb;                                               \
    const float x0e = g63 ? cpt : (x0 * pb);                                 \
    const float nb0 = cp0 + cp1;                                             \
    const float nb1 = fmaf(m3, cp3, cp1 + cp2);                              \
    b2 = cp2 + cp3;                                                          \
    b3 = fmaf(m5, cp5, cp3 + cp4);                                           \
    b4 = cp4 + cp5;                                                          \
    b5 = fmaf(m7, cp7, cp5 + cp6);                                           \
    b6 = cp6 + cp7;                                                          \
    b7 = fmaf(mn, yv, cp7 + x0e);                                            \
    bt = cpt;                                                                \
    b0 = nb0; b1 = nb1;                                                      \
    p1 = (QU).x; p3 = (QU).y; p5 = (QU).z; p7 = (QU).w;                      \
    pb = (QB);                                                               \
    u0 = dpp_shl1_f(nb0);                                                    \
    v = dpp_shl1_f(nb1 * p1);                                                \
  } while (0)

#define SYNCB do {                                                           \
    const float mA = fmaxf(fmaxf(b0, b1), b2);                               \
    const float mB = fmaxf(fmaxf(b3, b4), b5);                               \
    const float mC = fmaxf(fmaxf(b6, b7), bt);                               \
    const float m8 = fmaxf(fmaxf(mA, mB), mC);                               \
    const float mi = fmaxf(u0, v);                                           \
    const int e_res = (int)((__float_as_uint(m8) >> 23) & 255u) - 126;       \
    const int e_in =                                                         \
        (int)((__float_as_uint(mi) >> 23) & 255u) - 126 + di_g;              \
    const int e = (e_res > e_in) ? e_res : e_in;                             \
    F += e;                                                                  \
    const int Fp1 = dpp_shl1_i(F);                                           \
    const int d1 = g63 ? 0 : (Fp1 - F);                                      \
    const int s1 = (d1 > 4) ? (d1 - 4) : 0;                                  \
    F += s1;                                                                 \
    const int Fp2 = dpp_shl1_i(F);                                           \
    const int d2 = g63 ? 0 : (Fp2 - F);                                      \
    const int s2 = (d2 > 4) ? (d2 - 4) : 0;                                  \
    F += s2;                                                                 \
    const int sh = e + s1 + s2;                                              \
    b0 = ldexpf(b0, -sh); b1 = ldexpf(b1, -sh); b2 = ldexpf(b2, -sh);        \
    b3 = ldexpf(b3, -sh); b4 = ldexpf(b4, -sh); b5 = ldexpf(b5, -sh);        \
    b6 = ldexpf(b6, -sh); b7 = ldexpf(b7, -sh); bt = ldexpf(bt, -sh);        \
    u0 = ldexpf(u0, di_g - sh);                                              \
    v = ldexpf(v, di_g - sh);                                                \
    di_g = d2 - s2;                                                          \
  } while (0)

#define SLOTB(U, DI, RB) do {                                                \
    LEANB(q##U, RL(RB, (U) & 7), DI);                                        \
    q##U = gp[(size_t)(tt - 17 - U) * 64 + lane];                            \
  } while (0)

__global__ __launch_bounds__(128) void ctc_dp(const float4* __restrict__ packed,
                                              const float* __restrict__ blanks2,
                                              const int* __restrict__ labels,
                                              const int* __restrict__ widths,
                                              const int* __restrict__ lengths,
                                              float* __restrict__ out) {
  __shared__ float Alog[513];
  __shared__ float Blog[513];
  const int b = blockIdx.x;
  const int tid = threadIdx.x;
  const int wid = tid >> 6;
  const int lane = tid & 63;
  const int l8 = lane & 7;
  const int lpar = lane & 1;
  const bool g0 = (lane == 0);
  const bool g63 = (lane == 63);
  const int Tb = widths[b] >> 3;     // in [1536, 2048]
  const int s_end = 2 * lengths[b];
  const int tm = (Tb * 71) >> 7;     // meet row (fwd/bwd cost-balanced)
  const int* lab = labels + (b << 8);
  const int4 lb = *reinterpret_cast<const int4*>(lab + 4 * lane);
  const int pw = __shfl_up(lb.w, 1);
  const float m1 = (lane > 0 && lb.x != pw) ? 1.f : 0.f;
  const float m3 = (lb.y != lb.x) ? 1.f : 0.f;
  const float m5 = (lb.z != lb.y) ? 1.f : 0.f;
  const float m7 = (lb.w != lb.z) ? 1.f : 0.f;
  const float mdn = __shfl_down(m1, 1);
  const float mn = g63 ? 0.f : mdn;  // skip mask for s+2 = 8l+9

  const float4* gp = packed + (size_t)b * (T_ * 64);
  const float* gb = blanks2 + b * (2 * T_);

  if (wid == 0) {
    // ---------------- forward alpha: rows 0 .. tm-1 ----------------
    const float4 u0v = gp[lane];
    const float bl0 = gb[lpar];
    const float4 u1v = gp[64 + lane];
    const float bl1 = gb[2 + lpar];
    float4 q0 = gp[2 * 64 + lane],  q1 = gp[3 * 64 + lane];
    float4 q2 = gp[4 * 64 + lane],  q3 = gp[5 * 64 + lane];
    float4 q4 = gp[6 * 64 + lane],  q5 = gp[7 * 64 + lane];
    float4 q6 = gp[8 * 64 + lane],  q7 = gp[9 * 64 + lane];
    float4 q8 = gp[10 * 64 + lane], q9 = gp[11 * 64 + lane];
    float4 q10 = gp[12 * 64 + lane], q11 = gp[13 * 64 + lane];
    float4 q12 = gp[14 * 64 + lane], q13 = gp[15 * 64 + lane];
    float4 q14 = gp[16 * 64 + lane], q15 = gp[17 * 64 + lane];
    float rbA0 = gb[2 * (2 + l8)];
    float rbA1 = gb[2 * (10 + l8)];

    float a0 = 0.f, a1 = 0.f, a2 = 0.f, a3 = 0.f;
    float a4 = 0.f, a5 = 0.f, a6 = 0.f, a7 = 0.f, at = 0.f;
    int F = 0, di_g = 0;
    float b1_raw = 0.f;
    if (g0) { a0 = bl0; a1 = u0v.x; }
    float pb = bl1;
    float p1 = u1v.x, p3 = u1v.y, p5 = u1v.z, p7 = u1v.w;

    int tt = 1;
    for (; tt + 16 <= tm; tt += 16) {
      const float rbB0 = gb[2 * (tt + 17 + l8)];
      const float rbB1 = gb[2 * (tt + 25 + l8)];
      SLOTF(0, 0, rbA0);     SLOTF(1, di_g, rbA0);
      SLOTF(2, di_g, rbA0);  SLOTF(3, di_g, rbA0);
      SLOTF(4, di_g, rbA0);  SLOTF(5, di_g, rbA0);
      SLOTF(6, di_g, rbA0);  SLOTF(7, di_g, rbA0);
      SLOTF(8, di_g, rbA1);  SLOTF(9, di_g, rbA1);
      SLOTF(10, di_g, rbA1); SLOTF(11, di_g, rbA1);
      SLOTF(12, di_g, rbA1); SLOTF(13, di_g, rbA1);
      SLOTF(14, di_g, rbA1); SLOTF(15, di_g, rbA1);
      SYNCF;
      rbA0 = rbB0; rbA1 = rbB1;
    }
    if (tt + 0 < tm)  LEANF(q0,  RL(rbA0, 0), 0);
    if (tt + 1 < tm)  LEANF(q1,  RL(rbA0, 1), di_g);
    if (tt + 2 < tm)  LEANF(q2,  RL(rbA0, 2), di_g);
    if (tt + 3 < tm)  LEANF(q3,  RL(rbA0, 3), di_g);
    if (tt + 4 < tm)  LEANF(q4,  RL(rbA0, 4), di_g);
    if (tt + 5 < tm)  LEANF(q5,  RL(rbA0, 5), di_g);
    if (tt + 6 < tm)  LEANF(q6,  RL(rbA0, 6), di_g);
    if (tt + 7 < tm)  LEANF(q7,  RL(rbA0, 7), di_g);
    if (tt + 8 < tm)  LEANF(q8,  RL(rbA1, 0), di_g);
    if (tt + 9 < tm)  LEANF(q9,  RL(rbA1, 1), di_g);
    if (tt + 10 < tm) LEANF(q10, RL(rbA1, 2), di_g);
    if (tt + 11 < tm) LEANF(q11, RL(rbA1, 3), di_g);
    if (tt + 12 < tm) LEANF(q12, RL(rbA1, 4), di_g);
    if (tt + 13 < tm) LEANF(q13, RL(rbA1, 5), di_g);
    if (tt + 14 < tm) LEANF(q14, RL(rbA1, 6), di_g);

    const float Ff = (float)F;
    const int sb = 8 * lane;
    Alog[sb + 0] = (a0 > 0.f) ? lg2(a0) + Ff : -1.0e30f;
    Alog[sb + 1] = (a1 > 0.f) ? lg2(a1) + Ff : -1.0e30f;
    Alog[sb + 2] = (a2 > 0.f) ? lg2(a2) + Ff : -1.0e30f;
    Alog[sb + 3] = (a3 > 0.f) ? lg2(a3) + Ff : -1.0e30f;
    Alog[sb + 4] = (a4 > 0.f) ? lg2(a4) + Ff : -1.0e30f;
    Alog[sb + 5] = (a5 > 0.f) ? lg2(a5) + Ff : -1.0e30f;
    Alog[sb + 6] = (a6 > 0.f) ? lg2(a6) + Ff : -1.0e30f;
    Alog[sb + 7] = (a7 > 0.f) ? lg2(a7) + Ff : -1.0e30f;
    if (g63) Alog[512] = (at > 0.f) ? lg2(at) + Ff : -1.0e30f;
  } else {
    // ---------------- backward beta: rows Tb-1 .. tm ----------------
    const float4 brv = gp[(size_t)(Tb - 1) * 64 + lane];
    const float bli = gb[2 * (Tb - 1) + lpar];
    float4 q0 = gp[(size_t)(Tb - 2) * 64 + lane],  q1 = gp[(size_t)(Tb - 3) * 64 + lane];
    float4 q2 = gp[(size_t)(Tb - 4) * 64 + lane],  q3 = gp[(size_t)(Tb - 5) * 64 + lane];
    float4 q4 = gp[(size_t)(Tb - 6) * 64 + lane],  q5 = gp[(size_t)(Tb - 7) * 64 + lane];
    float4 q6 = gp[(size_t)(Tb - 8) * 64 + lane],  q7 = gp[(size_t)(Tb - 9) * 64 + lane];
    float4 q8 = gp[(size_t)(Tb - 10) * 64 + lane], q9 = gp[(size_t)(Tb - 11) * 64 + lane];
    float4 q10 = gp[(size_t)(Tb - 12) * 64 + lane], q11 = gp[(size_t)(Tb - 13) * 64 + lane];
    float4 q12 = gp[(size_t)(Tb - 14) * 64 + lane], q13 = gp[(size_t)(Tb - 15) * 64 + lane];
    float4 q14 = gp[(size_t)(Tb - 16) * 64 + lane], q15 = gp[(size_t)(Tb - 17) * 64 + lane];
    float rbA0 = gb[2 * (Tb - 2 - l8)];
    float rbA1 = gb[2 * (Tb - 10 - l8)];

    const int sb = 8 * lane;
    float b0 = (sb + 0 == s_end || sb + 0 == s_end - 1) ? 1.f : 0.f;
    float b1 = (sb + 1 == s_end || sb + 1 == s_end - 1) ? 1.f : 0.f;
    float b2 = (sb + 2 == s_end || sb + 2 == s_end - 1) ? 1.f : 0.f;
    float b3 = (sb + 3 == s_end || sb + 3 == s_end - 1) ? 1.f : 0.f;
    float b4 = (sb + 4 == s_end || sb + 4 == s_end - 1) ? 1.f : 0.f;
    float b5 = (sb + 5 == s_end || sb + 5 == s_end - 1) ? 1.f : 0.f;
    float b6 = (sb + 6 == s_end || sb + 6 == s_end - 1) ? 1.f : 0.f;
    float b7 = (sb + 7 == s_end || sb + 7 == s_end - 1) ? 1.f : 0.f;
    float bt = (g63 && s_end == 512) ? 1.f : 0.f;
    int F = 0, di_g = 0;

    float pb = bli;  // probs of row Tb-1 (first consumed)
    float p1 = brv.x, p3 = brv.y, p5 = brv.z, p7 = brv.w;
    float u0 = dpp_shl1_f(b0);
    float v = dpp_shl1_f(b1 * p1);

    int tt = Tb - 1;
    for (; tt - 15 >= tm; tt -= 16) {
      const float rbB0 = gb[2 * (tt - 17 - l8)];
      const float rbB1 = gb[2 * (tt - 25 - l8)];
      SLOTB(0, 0, rbA0);     SLOTB(1, di_g, rbA0);
      SLOTB(2, di_g, rbA0);  SLOTB(3, di_g, rbA0);
      SLOTB(4, di_g, rbA0);  SLOTB(5, di_g, rbA0);
      SLOTB(6, di_g, rbA0);  SLOTB(7, di_g, rbA0);
      SLOTB(8, di_g, rbA1);  SLOTB(9, di_g, rbA1);
      SLOTB(10, di_g, rbA1); SLOTB(11, di_g, rbA1);
      SLOTB(12, di_g, rbA1); SLOTB(13, di_g, rbA1);
      SLOTB(14, di_g, rbA1); SLOTB(15, di_g, rbA1);
      SYNCB;
      rbA0 = rbB0; rbA1 = rbB1;
    }
    if (tt - 0 >= tm)  LEANB(q0,  RL(rbA0, 0), 0);
    if (tt - 1 >= tm)  LEANB(q1,  RL(rbA0, 1), di_g);
    if (tt - 2 >= tm)  LEANB(q2,  RL(rbA0, 2), di_g);
    if (tt - 3 >= tm)  LEANB(q3,  RL(rbA0, 3), di_g);
    if (tt - 4 >= tm)  LEANB(q4,  RL(rbA0, 4), di_g);
    if (tt - 5 >= tm)  LEANB(q5,  RL(rbA0, 5), di_g);
    if (tt - 6 >= tm)  LEANB(q6,  RL(rbA0, 6), di_g);
    if (tt - 7 >= tm)  LEANB(q7,  RL(rbA0, 7), di_g);
    if (tt - 8 >= tm)  LEANB(q8,  RL(rbA1, 0), di_g);
    if (tt - 9 >= tm)  LEANB(q9,  RL(rbA1, 1), di_g);
    if (tt - 10 >= tm) LEANB(q10, RL(rbA1, 2), di_g);
    if (tt - 11 >= tm) LEANB(q11, RL(rbA1, 3), di_g);
    if (tt - 12 >= tm) LEANB(q12, RL(rbA1, 4), di_g);
    if (tt - 13 >= tm) LEANB(q13, RL(rbA1, 5), di_g);
    if (tt - 14 >= tm) LEANB(q14, RL(rbA1, 6), di_g);

    const float Ff = (float)F;
    Blog[sb + 0] = (b0 > 0.f) ? lg2(b0) + Ff : -1.0e30f;
    Blog[sb + 1] = (b1 > 0.f) ? lg2(b1) + Ff : -1.0e30f;
    Blog[sb + 2] = (b2 > 0.f) ? lg2(b2) + Ff : -1.0e30f;
    Blog[sb + 3] = (b3 > 0.f) ? lg2(b3) + Ff : -1.0e30f;
    Blog[sb + 4] = (b4 > 0.f) ? lg2(b4) + Ff : -1.0e30f;
    Blog[sb + 5] = (b5 > 0.f) ? lg2(b5) + Ff : -1.0e30f;
    Blog[sb + 6] = (b6 > 0.f) ? lg2(b6) + Ff : -1.0e30f;
    Blog[sb + 7] = (b7 > 0.f) ? lg2(b7) + Ff : -1.0e30f;
    if (g63) Blog[512] = (bt > 0.f) ? lg2(bt) + Ff : -1.0e30f;
  }

  __syncthreads();

  if (wid == 0) {
    // log2 P = logsumexp2_s (Alog[s] + Blog[s])
    const int sb = 8 * lane;
    float t0 = Alog[sb + 0] + Blog[sb + 0];
    float t1 = Alog[sb + 1] + Blog[sb + 1];
    float t2 = Alog[sb + 2] + Blog[sb + 2];
    float t3 = Alog[sb + 3] + Blog[sb + 3];
    float t4 = Alog[sb + 4] + Blog[sb + 4];
    float t5 = Alog[sb + 5] + Blog[sb + 5];
    float t6 = Alog[sb + 6] + Blog[sb + 6];
    float t7 = Alog[sb + 7] + Blog[sb + 7];
    float t8 = g63 ? (Alog[512] + Blog[512]) : -1.0e30f;
    float M = fmaxf(fmaxf(fmaxf(t0, t1), fmaxf(t2, t3)),
                    fmaxf(fmaxf(t4, t5), fmaxf(fmaxf(t6, t7), t8)));
#pragma unroll
    for (int off = 32; off >= 1; off >>= 1) M = fmaxf(M, __shfl_xor(M, off));
    float sm = ex2(t0 - M) + ex2(t1 - M) + ex2(t2 - M) + ex2(t3 - M) +
               ex2(t4 - M) + ex2(t5 - M) + ex2(t6 - M) + ex2(t7 - M) +
               ex2(t8 - M);
#pragma unroll
    for (int off = 32; off >= 1; off >>= 1) sm += __shfl_xor(sm, off);
    if (lane == 0)
      out[b] = -0.6931471805599453f * (M + lg2(sm));
  }
}

extern "C" void kernel_launch(void* const* d_in, const int* in_sizes, int n_in,
                              void* d_out, int out_size, void* d_ws, size_t ws_size,
                              hipStream_t stream) {
  const int* labels = (const int*)d_in[0];
  const float* logits = (const float*)d_in[1];
  const int* widths = (const int*)d_in[2];
  const int* lengths = (const int*)d_in[3];
  float* out = (float*)d_out;

  // ws layout: [blanks2: B*T*2 fp32 = 512KB][packed: B*T*64 float4 = 64MB]
  float* blanks2 = (float*)d_ws;
  float4* packed = (float4*)((char*)d_ws + (size_t)B_ * T_ * 2 * sizeof(float));

  gather_pack<<<B_ * T_, 64, 0, stream>>>(logits, labels, blanks2, packed);
  ctc_dp<<<B_, 128, 0, stream>>>(packed, blanks2, labels, widths, lengths, out);
}